// Round 8
// baseline (208.042 us; speedup 1.0000x reference)
//
#include <hip/hip_runtime.h>
#include <hip/hip_bf16.h>
#include <stdint.h>

typedef __attribute__((ext_vector_type(8))) short bf16x8;
typedef __attribute__((ext_vector_type(4))) float f32x4;
typedef __attribute__((ext_vector_type(8))) unsigned short u16x8;
typedef __attribute__((ext_vector_type(4))) unsigned short u16x4;

#define B_ 2
#define S_ 2048
#define E_ 2048
#define H_ 16
#define M_ 2048
#define D_ 128

#define MFMA16(a, b, c) __builtin_amdgcn_mfma_f32_16x16x32_bf16(a, b, c, 0, 0, 0)

__device__ inline unsigned short f2bf(float f) {
  union { float f; unsigned u; } v; v.f = f;
  unsigned r = v.u + 0x7FFFu + ((v.u >> 16) & 1u);
  return (unsigned short)(r >> 16);
}
__device__ inline float bf2f(unsigned short h) {
  union { unsigned u; float f; } v; v.u = ((unsigned)h) << 16;
  return v.f;
}

// packed f32x2 -> bf16x2 (RNE) via compiler intrinsic (lowers to v_cvt_pk_bf16_f32)
__device__ inline uint32_t pk2(float lo, float hi) {
  __hip_bfloat162 h2 = __float22bfloat162_rn(make_float2(lo, hi));
  uint32_t u;
  __builtin_memcpy(&u, &h2, 4);
  return u;
}

// native 2^x
__device__ inline float exp2a(float x) {
  float r;
  asm("v_exp_f32 %0, %1" : "=v"(r) : "v"(x));
  return r;
}

__device__ inline void gload_lds16(const void* g, void* l) {
  __builtin_amdgcn_global_load_lds(
      (__attribute__((address_space(1))) void*)g,
      (__attribute__((address_space(3))) void*)l, 16, 0, 0);
}

__device__ inline bf16x8 pack8(float4 f0, float4 f1) {
  bf16x8 o;
  o[0] = (short)f2bf(f0.x); o[1] = (short)f2bf(f0.y);
  o[2] = (short)f2bf(f0.z); o[3] = (short)f2bf(f0.w);
  o[4] = (short)f2bf(f1.x); o[5] = (short)f2bf(f1.y);
  o[6] = (short)f2bf(f1.z); o[7] = (short)f2bf(f1.w);
  return o;
}

__device__ inline float block_sum(float v) {
  __shared__ float red[4];
  #pragma unroll
  for (int o = 32; o > 0; o >>= 1) v += __shfl_xor(v, o);
  int tid = threadIdx.x;
  if ((tid & 63) == 0) red[tid >> 6] = v;
  __syncthreads();
  return red[0] + red[1] + red[2] + red[3];
}

// ---------------- f32 -> bf16 convert (wq) ----------------
__global__ __launch_bounds__(256) void f32_to_bf16_kernel(
    const float* __restrict__ in, unsigned short* __restrict__ out, int n4)
{
  int i = blockIdx.x * 256 + threadIdx.x;
  if (i >= n4) return;
  float4 v = ((const float4*)in)[i];
  u16x4 o;
  o[0] = f2bf(v.x); o[1] = f2bf(v.y); o[2] = f2bf(v.z); o[3] = f2bf(v.w);
  *(u16x4*)(out + (size_t)i * 4) = o;
}

// ---------------- RMSNorm(query) -> bf16 qn ----------------
__global__ __launch_bounds__(256) void rmsnorm_q_kernel(
    const float* __restrict__ x, const float* __restrict__ w,
    unsigned short* __restrict__ y)
{
  const int row = blockIdx.x;
  const int tid = threadIdx.x;
  const float* xr = x + (size_t)row * E_;
  float4 v0 = ((const float4*)xr)[tid * 2];
  float4 v1 = ((const float4*)xr)[tid * 2 + 1];
  float ss = v0.x*v0.x + v0.y*v0.y + v0.z*v0.z + v0.w*v0.w
           + v1.x*v1.x + v1.y*v1.y + v1.z*v1.z + v1.w*v1.w;
  float tot = block_sum(ss);
  float sc = rsqrtf(tot * (1.0f / E_) + 1e-5f);
  float vals[8] = {v0.x, v0.y, v0.z, v0.w, v1.x, v1.y, v1.z, v1.w};
  const float* wr = w + tid * 8;
  u16x8 o;
  #pragma unroll
  for (int j = 0; j < 8; ++j) o[j] = f2bf(vals[j] * sc * wr[j]);
  *(u16x8*)(y + (size_t)row * E_ + tid * 8) = o;
}

// ---------------- GEMM C[M,N] = A[M,K] @ B[N,K]^T (bf16 in, bf16 out) ----------------
__global__ __launch_bounds__(256) void gemm_qproj(
    const unsigned short* __restrict__ A, const unsigned short* __restrict__ B,
    unsigned short* __restrict__ C, int M, int N, int K)
{
  __shared__ __align__(16) unsigned short As[128 * 32];
  __shared__ __align__(16) unsigned short Bs[128 * 32];
  const int bm = blockIdx.x * 128;
  const int bn = blockIdx.y * 128;
  const int tid = threadIdx.x;
  const int wave = tid >> 6, lane = tid & 63;
  const int r = lane & 15, g = lane >> 4;
  const int wm = (wave >> 1) * 64, wn = (wave & 1) * 64;

  f32x4 acc[4][4] = {};

  for (int k0 = 0; k0 < K; k0 += 32) {
    #pragma unroll
    for (int inst = 0; inst < 2; ++inst) {
      int off = (wave * 2 + inst) * 1024 + lane * 16;  // byte offset in 8KB tile
      int row = off >> 6;
      int kbyt = off & 63;
      gload_lds16((const char*)A + ((size_t)(bm + row) * K + k0) * 2 + kbyt,
                  (char*)As + (wave * 2 + inst) * 1024);
      gload_lds16((const char*)B + ((size_t)(bn + row) * K + k0) * 2 + kbyt,
                  (char*)Bs + (wave * 2 + inst) * 1024);
    }
    __syncthreads();
    bf16x8 a[4], bb[4];
    #pragma unroll
    for (int m = 0; m < 4; ++m)
      a[m] = *(const bf16x8*)&As[(wm + m * 16 + r) * 32 + g * 8];
    #pragma unroll
    for (int n = 0; n < 4; ++n)
      bb[n] = *(const bf16x8*)&Bs[(wn + n * 16 + r) * 32 + g * 8];
    #pragma unroll
    for (int m = 0; m < 4; ++m)
      #pragma unroll
      for (int n = 0; n < 4; ++n)
        acc[m][n] = MFMA16(a[m], bb[n], acc[m][n]);
    __syncthreads();
  }
  #pragma unroll
  for (int m = 0; m < 4; ++m)
    #pragma unroll
    for (int n = 0; n < 4; ++n)
      #pragma unroll
      for (int i = 0; i < 4; ++i) {
        int row = bm + wm + m * 16 + g * 4 + i;
        int col = bn + wn + n * 16 + r;
        C[(size_t)row * N + col] = f2bf(acc[m][n][i]);
      }
}

// ---------------- fused per-head K AND V projections (one sp read) ----------------
// K: kout[h][m][d] = (sum_dd sp[h][m][dd] * wk[d][dd]) * beta/sqrt(D) * log2(e)
// V: vt[h][d][m]   =  sum_dd sp[h][m][dd] * wv[d][dd]
__global__ __launch_bounds__(256, 1) void proj_kv_kernel(
    const float* __restrict__ sp, const float* __restrict__ wk,
    const float* __restrict__ wv, const float* __restrict__ beta,
    unsigned short* __restrict__ kout, unsigned short* __restrict__ vtout)
{
  const int m0 = blockIdx.x * 128;
  const int h = blockIdx.y;
  const int tid = threadIdx.x, wave = tid >> 6, lane = tid & 63;
  const int r = lane & 15, g = lane >> 4;
  const int wm = (wave >> 1) * 64, wn = (wave & 1) * 64;
  const float* spb = sp + ((size_t)h * M_ + m0) * D_;
  const float kscale = beta[h] * 0.08838834764831845f * 1.4426950408889634f;
  f32x4 acck[4][4] = {};
  f32x4 accv[4][4] = {};
  #pragma unroll
  for (int kc = 0; kc < 4; ++kc) {
    bf16x8 a[4], bk[4], bv[4];
    #pragma unroll
    for (int m = 0; m < 4; ++m) {
      const float* p = spb + (size_t)(wm + m * 16 + r) * D_ + kc * 32 + g * 8;
      a[m] = pack8(*(const float4*)p, *(const float4*)(p + 4));
    }
    #pragma unroll
    for (int n = 0; n < 4; ++n) {
      const float* pk = wk + (size_t)(wn + n * 16 + r) * D_ + kc * 32 + g * 8;
      bk[n] = pack8(*(const float4*)pk, *(const float4*)(pk + 4));
      const float* pv = wv + (size_t)(wn + n * 16 + r) * D_ + kc * 32 + g * 8;
      bv[n] = pack8(*(const float4*)pv, *(const float4*)(pv + 4));
    }
    #pragma unroll
    for (int m = 0; m < 4; ++m)
      #pragma unroll
      for (int n = 0; n < 4; ++n) {
        acck[m][n] = MFMA16(a[m], bk[n], acck[m][n]);
        accv[m][n] = MFMA16(a[m], bv[n], accv[m][n]);
      }
  }
  #pragma unroll
  for (int m = 0; m < 4; ++m)
    #pragma unroll
    for (int n = 0; n < 4; ++n)
      #pragma unroll
      for (int i = 0; i < 4; ++i) {
        kout[((size_t)h * M_ + m0 + wm + m * 16 + g * 4 + i) * D_ + wn + n * 16 + r]
            = f2bf(acck[m][n][i] * kscale);
        vtout[((size_t)h * D_ + wn + n * 16 + r) * M_ + m0 + wm + m * 16 + g * 4 + i]
            = f2bf(accv[m][n][i]);
      }
}

// ---------------- flash attention over memory slots ----------------
// grid: (S/128, H, B); block 256 (4 waves x 32 q-rows each)
// LDS-traffic-minimized: 32 q-rows/wave so every K/V fragment read from LDS
// feeds 2 MFMAs (round-7's 16q/wave wasted 2x LDS BW — the binding pipe).
// Single-buffered K/V (48KB LDS) -> 3 blocks/CU; cross-block overlap hides
// the per-iteration vmcnt drain at the stage barrier.
__global__ __launch_bounds__(256, 3) void attn_kernel(
    const unsigned short* __restrict__ q,    // [B*S][E] bf16
    const unsigned short* __restrict__ kb,   // [H][M][D] bf16 (pre-scaled)
    const unsigned short* __restrict__ vtb,  // [H][D][M] bf16
    unsigned short* __restrict__ ret)        // [B*S][E] bf16
{
  __shared__ __align__(16) unsigned short Ks[64 * 128];   // 16KB
  __shared__ __align__(16) unsigned short Vs[128 * 64];   // 16KB
  __shared__ __align__(16) unsigned short Ps[4][32 * 64]; // 16KB
  const int s0 = blockIdx.x * 128;
  const int h = blockIdx.y;
  const int b = blockIdx.z;
  const int tid = threadIdx.x, wave = tid >> 6, lane = tid & 63;
  const int r = lane & 15, g = lane >> 4;
  const int fx = (r & 7) << 4;  // read/write XOR, row&7 == r&7 for all accesses

  // Q fragments: 2 x 16 rows per wave (q = wave*16 + r, and +64)
  bf16x8 qf0[4], qf1[4];
  {
    const unsigned short* qr0 =
        q + ((size_t)(b * S_) + s0 + wave * 16 + r) * E_ + h * D_;
    const unsigned short* qr1 = qr0 + (size_t)64 * E_;
    #pragma unroll
    for (int kc = 0; kc < 4; ++kc) {
      qf0[kc] = *(const bf16x8*)(qr0 + kc * 32 + g * 8);
      qf1[kc] = *(const bf16x8*)(qr1 + kc * 32 + g * 8);
    }
  }

  const char* Kh = (const char*)(kb + (size_t)h * M_ * D_);
  const char* Vh = (const char*)(vtb + (size_t)h * D_ * M_);
  char* Pw = (char*)Ps[wave];

  f32x4 o0[8] = {}, o1[8] = {};
  float lacc0 = 0.f, lacc1 = 0.f;

  auto stage = [&](int m0) {
    #pragma unroll
    for (int c = 0; c < 4; ++c) {
      int chunk = wave * 4 + c;
      int off = chunk * 1024 + lane * 16;
      {
        int row = off >> 8, cb = off & 255;
        gload_lds16(Kh + (size_t)(m0 + row) * 256 + (cb ^ ((row & 7) << 4)),
                    (char*)Ks + chunk * 1024);
      }
      {
        int row = off >> 7, cb = off & 127;
        gload_lds16(Vh + (size_t)row * (M_ * 2) + (size_t)m0 * 2 + (cb ^ ((row & 7) << 4)),
                    (char*)Vs + chunk * 1024);
      }
    }
  };

  for (int t = 0; t < M_ / 64; ++t) {
    stage(t * 64);
    __syncthreads();  // drains vmcnt(0): tile loaded for all waves

    const char* Kc = (const char*)Ks;
    const char* Vc = (const char*)Vs;

    // ---- S^T = K @ Q^T : lane (r,g) gets S^T[kv=16nf+4g+i][q=r(+16)]
    f32x4 sA[4] = {}, sB[4] = {};
    __builtin_amdgcn_s_setprio(1);
    #pragma unroll
    for (int nf = 0; nf < 4; ++nf)
      #pragma unroll
      for (int kc = 0; kc < 4; ++kc) {
        bf16x8 kf = *(const bf16x8*)(Kc + (nf * 16 + r) * 256 + ((kc * 64 + g * 16) ^ fx));
        sA[nf] = MFMA16(kf, qf0[kc], sA[nf]);
        sB[nf] = MFMA16(kf, qf1[kc], sB[nf]);
      }
    __builtin_amdgcn_s_setprio(0);

    // ---- P = 2^s (lane-local l); cvt_pk pack; b64 write to LDS [q][m] (swizzled)
    #pragma unroll
    for (int nf = 0; nf < 4; ++nf) {
      float a0 = exp2a(sA[nf][0]), a1 = exp2a(sA[nf][1]),
            a2 = exp2a(sA[nf][2]), a3 = exp2a(sA[nf][3]);
      lacc0 += (a0 + a1) + (a2 + a3);
      uint2 wa = make_uint2(pk2(a0, a1), pk2(a2, a3));
      *(uint2*)(Pw + r * 128 + ((nf * 32 + g * 8) ^ fx)) = wa;

      float b0 = exp2a(sB[nf][0]), b1 = exp2a(sB[nf][1]),
            b2 = exp2a(sB[nf][2]), b3 = exp2a(sB[nf][3]);
      lacc1 += (b0 + b1) + (b2 + b3);
      uint2 wb = make_uint2(pk2(b0, b1), pk2(b2, b3));
      *(uint2*)(Pw + (16 + r) * 128 + ((nf * 32 + g * 8) ^ fx)) = wb;
    }

    // ---- O += P @ V  (A = P from LDS, B = V^T from LDS)
    bf16x8 pa00 = *(const bf16x8*)(Pw + r * 128 + ((g * 16) ^ fx));
    bf16x8 pa01 = *(const bf16x8*)(Pw + r * 128 + ((64 + g * 16) ^ fx));
    bf16x8 pa10 = *(const bf16x8*)(Pw + (16 + r) * 128 + ((g * 16) ^ fx));
    bf16x8 pa11 = *(const bf16x8*)(Pw + (16 + r) * 128 + ((64 + g * 16) ^ fx));
    __builtin_amdgcn_s_setprio(1);
    #pragma unroll
    for (int nf2 = 0; nf2 < 8; ++nf2) {
      bf16x8 vf0 = *(const bf16x8*)(Vc + (nf2 * 16 + r) * 128 + ((g * 16) ^ fx));
      bf16x8 vf1 = *(const bf16x8*)(Vc + (nf2 * 16 + r) * 128 + ((64 + g * 16) ^ fx));
      o0[nf2] = MFMA16(pa00, vf0, o0[nf2]);
      o0[nf2] = MFMA16(pa01, vf1, o0[nf2]);
      o1[nf2] = MFMA16(pa10, vf0, o1[nf2]);
      o1[nf2] = MFMA16(pa11, vf1, o1[nf2]);
    }
    __builtin_amdgcn_s_setprio(0);
    __syncthreads();  // all reads of this tile done before next stage overwrites
  }

  // ---- epilogue: reduce l across g; transpose l via LDS; normalize; store
  float l0 = lacc0; l0 += __shfl_xor(l0, 16); l0 += __shfl_xor(l0, 32);
  float l1 = lacc1; l1 += __shfl_xor(l1, 16); l1 += __shfl_xor(l1, 32);
  float* Ls = (float*)Pw;  // reuse P scratch (per-wave, loop done)
  if (lane < 16) { Ls[r] = l0; Ls[16 + r] = l1; }
  float invA[4], invB[4];
  #pragma unroll
  for (int i = 0; i < 4; ++i) {
    invA[i] = 1.0f / Ls[g * 4 + i];
    invB[i] = 1.0f / Ls[16 + g * 4 + i];
  }
  {
    unsigned short* rr = ret + ((size_t)(b * S_) + s0 + wave * 16) * E_ + h * D_;
    #pragma unroll
    for (int nf2 = 0; nf2 < 8; ++nf2)
      #pragma unroll
      for (int i = 0; i < 4; ++i)
        rr[(size_t)(g * 4 + i) * E_ + nf2 * 16 + r] = f2bf(o0[nf2][i] * invA[i]);
  }
  {
    unsigned short* rr = ret + ((size_t)(b * S_) + s0 + 64 + wave * 16) * E_ + h * D_;
    #pragma unroll
    for (int nf2 = 0; nf2 < 8; ++nf2)
      #pragma unroll
      for (int i = 0; i < 4; ++i)
        rr[(size_t)(g * 4 + i) * E_ + nf2 * 16 + r] = f2bf(o1[nf2][i] * invB[i]);
  }
}

// ---------------- final: out = query + rmsnorm(retrieved)*w ----------------
__global__ __launch_bounds__(256) void final_kernel(
    const unsigned short* __restrict__ ret, const float* __restrict__ w,
    const float* __restrict__ query, float* __restrict__ out)
{
  const int row = blockIdx.x;
  const int tid = threadIdx.x;
  u16x8 hv = *(const u16x8*)(ret + (size_t)row * E_ + tid * 8);
  float x[8];
  float ss = 0.f;
  #pragma unroll
  for (int j = 0; j < 8; ++j) { x[j] = bf2f(hv[j]); ss += x[j] * x[j]; }
  float tot = block_sum(ss);
  float sc = rsqrtf(tot * (1.0f / E_) + 1e-5f);
  const float* qr = query + (size_t)row * E_ + tid * 8;
  const float* wr = w + tid * 8;
  float o[8];
  #pragma unroll
  for (int j = 0; j < 8; ++j) o[j] = qr[j] + x[j] * sc * wr[j];
  float4* op = (float4*)(out + (size_t)row * E_ + tid * 8);
  op[0] = make_float4(o[0], o[1], o[2], o[3]);
  op[1] = make_float4(o[4], o[5], o[6], o[7]);
}

extern "C" void kernel_launch(void* const* d_in, const int* in_sizes, int n_in,
                              void* d_out, int out_size, void* d_ws, size_t ws_size,
                              hipStream_t stream) {
  const float* query = (const float*)d_in[0];
  const float* sp    = (const float*)d_in[1];
  const float* wq    = (const float*)d_in[2];
  const float* wk    = (const float*)d_in[3];
  const float* wv    = (const float*)d_in[4];
  const float* beta  = (const float*)d_in[5];
  const float* nqw   = (const float*)d_in[6];
  const float* nrw   = (const float*)d_in[7];
  float* out = (float*)d_out;

  char* ws = (char*)d_ws;
  unsigned short* wqb = (unsigned short*)(ws + 0);                      // 8 MB
  unsigned short* qn  = (unsigned short*)(ws + ((size_t)8 << 20));     // 16 MB
  unsigned short* qb  = (unsigned short*)(ws + ((size_t)24 << 20));    // 16 MB
  unsigned short* kb  = (unsigned short*)(ws + ((size_t)40 << 20));    // 8 MB
  unsigned short* vtb = (unsigned short*)(ws + ((size_t)48 << 20));    // 8 MB
  unsigned short* ret = qn;  // reuse (qn dead after q-GEMM)

  f32_to_bf16_kernel<<<4096, 256, 0, stream>>>(wq, wqb, E_ * E_ / 4);
  rmsnorm_q_kernel<<<B_ * S_, 256, 0, stream>>>(query, nqw, qn);
  gemm_qproj<<<dim3((B_ * S_) / 128, E_ / 128), 256, 0, stream>>>(
      qn, wqb, qb, B_ * S_, E_, E_);
  proj_kv_kernel<<<dim3(M_ / 128, H_), 256, 0, stream>>>(sp, wk, wv, beta, kb, vtb);
  attn_kernel<<<dim3(S_ / 128, H_, B_), 256, 0, stream>>>(qb, kb, vtb, ret);
  final_kernel<<<B_ * S_, 256, 0, stream>>>(ret, nrw, query, out);
}

// Round 9
// 168.179 us; speedup vs baseline: 1.2370x; 1.2370x over previous
//
#include <hip/hip_runtime.h>
#include <hip/hip_bf16.h>
#include <stdint.h>

typedef __attribute__((ext_vector_type(8))) short bf16x8;
typedef __attribute__((ext_vector_type(4))) float f32x4;
typedef __attribute__((ext_vector_type(8))) unsigned short u16x8;
typedef __attribute__((ext_vector_type(4))) unsigned short u16x4;

#define B_ 2
#define S_ 2048
#define E_ 2048
#define H_ 16
#define M_ 2048
#define D_ 128

#define MFMA16(a, b, c) __builtin_amdgcn_mfma_f32_16x16x32_bf16(a, b, c, 0, 0, 0)

__device__ inline unsigned short f2bf(float f) {
  union { float f; unsigned u; } v; v.f = f;
  unsigned r = v.u + 0x7FFFu + ((v.u >> 16) & 1u);
  return (unsigned short)(r >> 16);
}
__device__ inline float bf2f(unsigned short h) {
  union { unsigned u; float f; } v; v.u = ((unsigned)h) << 16;
  return v.f;
}

// packed f32x2 -> bf16x2 (RNE) via compiler intrinsic (lowers to v_cvt_pk_bf16_f32)
__device__ inline uint32_t pk2(float lo, float hi) {
  __hip_bfloat162 h2 = __float22bfloat162_rn(make_float2(lo, hi));
  uint32_t u;
  __builtin_memcpy(&u, &h2, 4);
  return u;
}

// native 2^x
__device__ inline float exp2a(float x) {
  float r;
  asm("v_exp_f32 %0, %1" : "=v"(r) : "v"(x));
  return r;
}

__device__ inline void gload_lds16(const void* g, void* l) {
  __builtin_amdgcn_global_load_lds(
      (__attribute__((address_space(1))) void*)g,
      (__attribute__((address_space(3))) void*)l, 16, 0, 0);
}

__device__ inline bf16x8 pack8(float4 f0, float4 f1) {
  bf16x8 o;
  o[0] = (short)f2bf(f0.x); o[1] = (short)f2bf(f0.y);
  o[2] = (short)f2bf(f0.z); o[3] = (short)f2bf(f0.w);
  o[4] = (short)f2bf(f1.x); o[5] = (short)f2bf(f1.y);
  o[6] = (short)f2bf(f1.z); o[7] = (short)f2bf(f1.w);
  return o;
}

__device__ inline float block_sum(float v) {
  __shared__ float red[4];
  #pragma unroll
  for (int o = 32; o > 0; o >>= 1) v += __shfl_xor(v, o);
  int tid = threadIdx.x;
  if ((tid & 63) == 0) red[tid >> 6] = v;
  __syncthreads();
  return red[0] + red[1] + red[2] + red[3];
}

// ---------------- f32 -> bf16 convert (wq) ----------------
__global__ __launch_bounds__(256) void f32_to_bf16_kernel(
    const float* __restrict__ in, unsigned short* __restrict__ out, int n4)
{
  int i = blockIdx.x * 256 + threadIdx.x;
  if (i >= n4) return;
  float4 v = ((const float4*)in)[i];
  u16x4 o;
  o[0] = f2bf(v.x); o[1] = f2bf(v.y); o[2] = f2bf(v.z); o[3] = f2bf(v.w);
  *(u16x4*)(out + (size_t)i * 4) = o;
}

// ---------------- RMSNorm(query) -> bf16 qn ----------------
__global__ __launch_bounds__(256) void rmsnorm_q_kernel(
    const float* __restrict__ x, const float* __restrict__ w,
    unsigned short* __restrict__ y)
{
  const int row = blockIdx.x;
  const int tid = threadIdx.x;
  const float* xr = x + (size_t)row * E_;
  float4 v0 = ((const float4*)xr)[tid * 2];
  float4 v1 = ((const float4*)xr)[tid * 2 + 1];
  float ss = v0.x*v0.x + v0.y*v0.y + v0.z*v0.z + v0.w*v0.w
           + v1.x*v1.x + v1.y*v1.y + v1.z*v1.z + v1.w*v1.w;
  float tot = block_sum(ss);
  float sc = rsqrtf(tot * (1.0f / E_) + 1e-5f);
  float vals[8] = {v0.x, v0.y, v0.z, v0.w, v1.x, v1.y, v1.z, v1.w};
  const float* wr = w + tid * 8;
  u16x8 o;
  #pragma unroll
  for (int j = 0; j < 8; ++j) o[j] = f2bf(vals[j] * sc * wr[j]);
  *(u16x8*)(y + (size_t)row * E_ + tid * 8) = o;
}

// ---------------- GEMM C[M,N] = A[M,K] @ B[N,K]^T (bf16 in, bf16 out) ----------------
// BK=64 (half the barrier drains), XOR-swizzled LDS (stage-source + read pair,
// same (row&7)<<4 involution as attn: without it the 128B row stride is a
// 16-way bank conflict), 1D grid with chunk-XCD swizzle (nwg=512 % 8 == 0).
__global__ __launch_bounds__(256) void gemm_qproj(
    const unsigned short* __restrict__ A, const unsigned short* __restrict__ B,
    unsigned short* __restrict__ C, int M, int N, int K)
{
  __shared__ __align__(16) unsigned short As[128 * 64];  // 16KB
  __shared__ __align__(16) unsigned short Bs[128 * 64];  // 16KB
  const int nwg = gridDim.x;
  const int cpx = nwg >> 3;
  const int swz = (blockIdx.x & 7) * cpx + (blockIdx.x >> 3);
  const int mt = M >> 7;                 // M/128 tiles (fastest: share B-panel)
  const int bm = (swz % mt) * 128;
  const int bn = (swz / mt) * 128;
  const int tid = threadIdx.x;
  const int wave = tid >> 6, lane = tid & 63;
  const int r = lane & 15, g = lane >> 4;
  const int wm = (wave >> 1) * 64, wn = (wave & 1) * 64;
  const int fx = (r & 7) << 4;

  f32x4 acc[4][4] = {};

  for (int k0 = 0; k0 < K; k0 += 64) {
    #pragma unroll
    for (int c = 0; c < 4; ++c) {
      int chunk = wave * 4 + c;             // 16 chunks x 1KB per matrix
      int off = chunk * 1024 + lane * 16;   // byte offset in 16KB tile
      int row = off >> 7;                   // 128B per row
      int cb = (off & 127) ^ ((row & 7) << 4);  // pre-swizzled source
      gload_lds16((const char*)A + ((size_t)(bm + row) * K + k0) * 2 + cb,
                  (char*)As + chunk * 1024);
      gload_lds16((const char*)B + ((size_t)(bn + row) * K + k0) * 2 + cb,
                  (char*)Bs + chunk * 1024);
    }
    __syncthreads();
    #pragma unroll
    for (int kc = 0; kc < 2; ++kc) {
      bf16x8 a[4], bb[4];
      #pragma unroll
      for (int m = 0; m < 4; ++m)
        a[m] = *(const bf16x8*)((const char*)As + (wm + m * 16 + r) * 128
                                + ((kc * 64 + g * 16) ^ fx));
      #pragma unroll
      for (int n = 0; n < 4; ++n)
        bb[n] = *(const bf16x8*)((const char*)Bs + (wn + n * 16 + r) * 128
                                 + ((kc * 64 + g * 16) ^ fx));
      #pragma unroll
      for (int m = 0; m < 4; ++m)
        #pragma unroll
        for (int n = 0; n < 4; ++n)
          acc[m][n] = MFMA16(a[m], bb[n], acc[m][n]);
    }
    __syncthreads();
  }
  #pragma unroll
  for (int m = 0; m < 4; ++m)
    #pragma unroll
    for (int n = 0; n < 4; ++n)
      #pragma unroll
      for (int i = 0; i < 4; ++i) {
        int row = bm + wm + m * 16 + g * 4 + i;
        int col = bn + wn + n * 16 + r;
        C[(size_t)row * N + col] = f2bf(acc[m][n][i]);
      }
}

// ---------------- fused per-head K AND V projections (one sp read) ----------------
// K: kout[h][m][d] = (sum_dd sp[h][m][dd] * wk[d][dd]) * beta/sqrt(D) * log2(e)
// V: vt[h][d][m]   =  sum_dd sp[h][m][dd] * wv[d][dd]
__global__ __launch_bounds__(256, 1) void proj_kv_kernel(
    const float* __restrict__ sp, const float* __restrict__ wk,
    const float* __restrict__ wv, const float* __restrict__ beta,
    unsigned short* __restrict__ kout, unsigned short* __restrict__ vtout)
{
  const int m0 = blockIdx.x * 128;
  const int h = blockIdx.y;
  const int tid = threadIdx.x, wave = tid >> 6, lane = tid & 63;
  const int r = lane & 15, g = lane >> 4;
  const int wm = (wave >> 1) * 64, wn = (wave & 1) * 64;
  const float* spb = sp + ((size_t)h * M_ + m0) * D_;
  const float kscale = beta[h] * 0.08838834764831845f * 1.4426950408889634f;
  f32x4 acck[4][4] = {};
  f32x4 accv[4][4] = {};
  #pragma unroll
  for (int kc = 0; kc < 4; ++kc) {
    bf16x8 a[4], bk[4], bv[4];
    #pragma unroll
    for (int m = 0; m < 4; ++m) {
      const float* p = spb + (size_t)(wm + m * 16 + r) * D_ + kc * 32 + g * 8;
      a[m] = pack8(*(const float4*)p, *(const float4*)(p + 4));
    }
    #pragma unroll
    for (int n = 0; n < 4; ++n) {
      const float* pk = wk + (size_t)(wn + n * 16 + r) * D_ + kc * 32 + g * 8;
      bk[n] = pack8(*(const float4*)pk, *(const float4*)(pk + 4));
      const float* pv = wv + (size_t)(wn + n * 16 + r) * D_ + kc * 32 + g * 8;
      bv[n] = pack8(*(const float4*)pv, *(const float4*)(pv + 4));
    }
    #pragma unroll
    for (int m = 0; m < 4; ++m)
      #pragma unroll
      for (int n = 0; n < 4; ++n) {
        acck[m][n] = MFMA16(a[m], bk[n], acck[m][n]);
        accv[m][n] = MFMA16(a[m], bv[n], accv[m][n]);
      }
  }
  #pragma unroll
  for (int m = 0; m < 4; ++m)
    #pragma unroll
    for (int n = 0; n < 4; ++n)
      #pragma unroll
      for (int i = 0; i < 4; ++i) {
        kout[((size_t)h * M_ + m0 + wm + m * 16 + g * 4 + i) * D_ + wn + n * 16 + r]
            = f2bf(acck[m][n][i] * kscale);
        vtout[((size_t)h * D_ + wn + n * 16 + r) * M_ + m0 + wm + m * 16 + g * 4 + i]
            = f2bf(accv[m][n][i]);
      }
}

// ---------------- flash attention over memory slots ----------------
// round-7 version (best measured, 89.3us): grid (S/128, H, B); block 512
// (8 waves x 16 q-rows); double-buffered K/V via global_load_lds (XOR-swizzled
// both sides); swapped QK^T; no-max exp2 softmax; P via per-wave LDS.
__global__ __launch_bounds__(512, 4) void attn_kernel(
    const unsigned short* __restrict__ q,    // [B*S][E] bf16
    const unsigned short* __restrict__ kb,   // [H][M][D] bf16 (pre-scaled)
    const unsigned short* __restrict__ vtb,  // [H][D][M] bf16
    unsigned short* __restrict__ ret)        // [B*S][E] bf16
{
  __shared__ __align__(16) unsigned short Ks[2][64 * 128];   // 2 x 16KB
  __shared__ __align__(16) unsigned short Vs[2][128 * 64];   // 2 x 16KB
  __shared__ __align__(16) unsigned short Ps[8][16 * 64];    // 16KB
  const int s0 = blockIdx.x * 128;
  const int h = blockIdx.y;
  const int b = blockIdx.z;
  const int tid = threadIdx.x, wave = tid >> 6, lane = tid & 63;
  const int r = lane & 15, g = lane >> 4;
  const int fx = (r & 7) << 4;  // read/write XOR, row&7 == r&7 for all accesses

  // Q fragment: 16 rows per wave (q = wave*16 + r)
  bf16x8 qf[4];
  {
    const unsigned short* qr0 =
        q + ((size_t)(b * S_) + s0 + wave * 16 + r) * E_ + h * D_;
    #pragma unroll
    for (int kc = 0; kc < 4; ++kc)
      qf[kc] = *(const bf16x8*)(qr0 + kc * 32 + g * 8);
  }

  const char* Kh = (const char*)(kb + (size_t)h * M_ * D_);
  const char* Vh = (const char*)(vtb + (size_t)h * D_ * M_);
  char* Pw = (char*)Ps[wave];

  f32x4 o[8] = {};
  float lacc = 0.f;

  auto stage = [&](int buf, int m0) {
    #pragma unroll
    for (int c = 0; c < 2; ++c) {
      int chunk = wave * 2 + c;
      int off = chunk * 1024 + lane * 16;
      {
        int row = off >> 8, cb = off & 255;
        gload_lds16(Kh + (size_t)(m0 + row) * 256 + (cb ^ ((row & 7) << 4)),
                    (char*)Ks[buf] + chunk * 1024);
      }
      {
        int row = off >> 7, cb = off & 127;
        gload_lds16(Vh + (size_t)row * (M_ * 2) + (size_t)m0 * 2 + (cb ^ ((row & 7) << 4)),
                    (char*)Vs[buf] + chunk * 1024);
      }
    }
  };

  stage(0, 0);
  __syncthreads();

  int cur = 0;
  for (int t = 0; t < M_ / 64; ++t) {
    if (t + 1 < M_ / 64) stage(cur ^ 1, (t + 1) * 64);

    const char* Kc = (const char*)Ks[cur];
    const char* Vc = (const char*)Vs[cur];

    // ---- S^T = K @ Q^T : lane (r,g) gets S^T[kv=16nf+4g+i][q=r]
    f32x4 sA[4] = {};
    __builtin_amdgcn_s_setprio(1);
    #pragma unroll
    for (int nf = 0; nf < 4; ++nf)
      #pragma unroll
      for (int kc = 0; kc < 4; ++kc) {
        bf16x8 kf = *(const bf16x8*)(Kc + (nf * 16 + r) * 256 + ((kc * 64 + g * 16) ^ fx));
        sA[nf] = MFMA16(kf, qf[kc], sA[nf]);
      }
    __builtin_amdgcn_s_setprio(0);

    // ---- P = 2^s (lane-local l); cvt_pk pack; b64 write to LDS [q][m] (swizzled)
    #pragma unroll
    for (int nf = 0; nf < 4; ++nf) {
      float a0 = exp2a(sA[nf][0]), a1 = exp2a(sA[nf][1]),
            a2 = exp2a(sA[nf][2]), a3 = exp2a(sA[nf][3]);
      lacc += (a0 + a1) + (a2 + a3);
      uint2 wa = make_uint2(pk2(a0, a1), pk2(a2, a3));
      *(uint2*)(Pw + r * 128 + ((nf * 32 + g * 8) ^ fx)) = wa;
    }

    // ---- O += P @ V  (A = P from LDS, B = V^T from LDS)
    bf16x8 pa0 = *(const bf16x8*)(Pw + r * 128 + ((g * 16) ^ fx));
    bf16x8 pa1 = *(const bf16x8*)(Pw + r * 128 + ((64 + g * 16) ^ fx));
    __builtin_amdgcn_s_setprio(1);
    #pragma unroll
    for (int nf2 = 0; nf2 < 8; ++nf2) {
      bf16x8 vf0 = *(const bf16x8*)(Vc + (nf2 * 16 + r) * 128 + ((g * 16) ^ fx));
      bf16x8 vf1 = *(const bf16x8*)(Vc + (nf2 * 16 + r) * 128 + ((64 + g * 16) ^ fx));
      o[nf2] = MFMA16(pa0, vf0, o[nf2]);
      o[nf2] = MFMA16(pa1, vf1, o[nf2]);
    }
    __builtin_amdgcn_s_setprio(0);
    __syncthreads();
    cur ^= 1;
  }

  // ---- epilogue: reduce l across g; transpose l via LDS; normalize; store
  float l0 = lacc; l0 += __shfl_xor(l0, 16); l0 += __shfl_xor(l0, 32);
  float* Ls = (float*)Pw;  // reuse P scratch (per-wave, loop done)
  if (lane < 16) Ls[r] = l0;
  float invA[4];
  #pragma unroll
  for (int i = 0; i < 4; ++i) invA[i] = 1.0f / Ls[g * 4 + i];
  unsigned short* rr = ret + ((size_t)(b * S_) + s0 + wave * 16) * E_ + h * D_;
  #pragma unroll
  for (int nf2 = 0; nf2 < 8; ++nf2)
    #pragma unroll
    for (int i = 0; i < 4; ++i)
      rr[(size_t)(g * 4 + i) * E_ + nf2 * 16 + r] = f2bf(o[nf2][i] * invA[i]);
}

// ---------------- final: out = query + rmsnorm(retrieved)*w ----------------
__global__ __launch_bounds__(256) void final_kernel(
    const unsigned short* __restrict__ ret, const float* __restrict__ w,
    const float* __restrict__ query, float* __restrict__ out)
{
  const int row = blockIdx.x;
  const int tid = threadIdx.x;
  u16x8 hv = *(const u16x8*)(ret + (size_t)row * E_ + tid * 8);
  float x[8];
  float ss = 0.f;
  #pragma unroll
  for (int j = 0; j < 8; ++j) { x[j] = bf2f(hv[j]); ss += x[j] * x[j]; }
  float tot = block_sum(ss);
  float sc = rsqrtf(tot * (1.0f / E_) + 1e-5f);
  const float* qr = query + (size_t)row * E_ + tid * 8;
  const float* wr = w + tid * 8;
  float o[8];
  #pragma unroll
  for (int j = 0; j < 8; ++j) o[j] = qr[j] + x[j] * sc * wr[j];
  float4* op = (float4*)(out + (size_t)row * E_ + tid * 8);
  op[0] = make_float4(o[0], o[1], o[2], o[3]);
  op[1] = make_float4(o[4], o[5], o[6], o[7]);
}

extern "C" void kernel_launch(void* const* d_in, const int* in_sizes, int n_in,
                              void* d_out, int out_size, void* d_ws, size_t ws_size,
                              hipStream_t stream) {
  const float* query = (const float*)d_in[0];
  const float* sp    = (const float*)d_in[1];
  const float* wq    = (const float*)d_in[2];
  const float* wk    = (const float*)d_in[3];
  const float* wv    = (const float*)d_in[4];
  const float* beta  = (const float*)d_in[5];
  const float* nqw   = (const float*)d_in[6];
  const float* nrw   = (const float*)d_in[7];
  float* out = (float*)d_out;

  char* ws = (char*)d_ws;
  unsigned short* wqb = (unsigned short*)(ws + 0);                      // 8 MB
  unsigned short* qn  = (unsigned short*)(ws + ((size_t)8 << 20));     // 16 MB
  unsigned short* qb  = (unsigned short*)(ws + ((size_t)24 << 20));    // 16 MB
  unsigned short* kb  = (unsigned short*)(ws + ((size_t)40 << 20));    // 8 MB
  unsigned short* vtb = (unsigned short*)(ws + ((size_t)48 << 20));    // 8 MB
  unsigned short* ret = qn;  // reuse (qn dead after q-GEMM)

  f32_to_bf16_kernel<<<4096, 256, 0, stream>>>(wq, wqb, E_ * E_ / 4);
  rmsnorm_q_kernel<<<B_ * S_, 256, 0, stream>>>(query, nqw, qn);
  gemm_qproj<<<(B_ * S_ / 128) * (E_ / 128), 256, 0, stream>>>(
      qn, wqb, qb, B_ * S_, E_, E_);
  proj_kv_kernel<<<dim3(M_ / 128, H_), 256, 0, stream>>>(sp, wk, wv, beta, kb, vtb);
  attn_kernel<<<dim3(S_ / 128, H_, B_), 512, 0, stream>>>(qb, kb, vtb, ret);
  final_kernel<<<B_ * S_, 256, 0, stream>>>(ret, nrw, query, out);
}